// Round 5
// baseline (489.394 us; speedup 1.0000x reference)
//
#include <hip/hip_runtime.h>
#include <hip/hip_bf16.h>

typedef __attribute__((ext_vector_type(4))) float f32x4;
typedef __attribute__((ext_vector_type(8))) short bf16x8;

#define VOCAB 32000
#define DIMS 1024
#define BATCH 2
#define SEQ 2048
#define ROWS (BATCH * SEQ)  // 4096
#define NC 128              // cumsum chunks per sequence
#define CL 16               // chunk length; NC*CL == SEQ

// ---------- helpers ----------
static __device__ __forceinline__ unsigned short f2bf(float f) {
  unsigned int u = __float_as_uint(f);
  unsigned int r = u + 0x7fffu + ((u >> 16) & 1u);
  return (unsigned short)(r >> 16);
}

// ---------- fp32 -> bf16 bulk convert ----------
__global__ void cvt_f32_bf16(const float* __restrict__ src,
                             unsigned short* __restrict__ dst, int n4) {
  int i = blockIdx.x * blockDim.x + threadIdx.x;
  int stride = gridDim.x * blockDim.x;
  for (; i < n4; i += stride) {
    float4 v = ((const float4*)src)[i];
    ushort4 o = {f2bf(v.x), f2bf(v.y), f2bf(v.z), f2bf(v.w)};
    ((ushort4*)dst)[i] = o;
  }
}

// ---------- embedding gather + convert ----------
__global__ void gather_emb(const int* __restrict__ idx,
                           const float* __restrict__ emb,
                           unsigned short* __restrict__ eB) {
  const int row = blockIdx.x;
  const int t = threadIdx.x;
  const int token = idx[row];
  const float4* src = (const float4*)(emb + (size_t)token * DIMS);
  float4 v = src[t];
  ushort4 o = {f2bf(v.x), f2bf(v.y), f2bf(v.z), f2bf(v.w)};
  ((ushort4*)(eB + (size_t)row * DIMS))[t] = o;
}

// ---------- old 128x128 NT GEMM (kept for the small V projection) ----------
__global__ __launch_bounds__(256) void gemm_bt(
    const unsigned short* __restrict__ A, const unsigned short* __restrict__ B,
    float* __restrict__ C, const float* __restrict__ bias, int K, int ldC) {
  __shared__ __align__(16) unsigned short sA[128 * 32];
  __shared__ __align__(16) unsigned short sB[128 * 32];

  const int tid = threadIdx.x;
  const int lane = tid & 63;
  const int w = tid >> 6;
  const int wr = w >> 1;
  const int wc = w & 1;
  const long mBase = (long)blockIdx.x * 128;
  const long nBase = (long)blockIdx.y * 128;

  const unsigned short* Ati = A + mBase * K;
  const unsigned short* Bti = B + nBase * K;

  const int srow0 = w * 32;
  const int sr = lane >> 2;
  const int ske = (lane & 3) * 8;

  f32x4 acc[4][4] = {};

  for (int kt = 0; kt < K; kt += 32) {
    __syncthreads();
#pragma unroll
    for (int i = 0; i < 2; ++i) {
      const int r = srow0 + i * 16;
      __builtin_amdgcn_global_load_lds(
          (const __attribute__((address_space(1))) unsigned int*)(
              Ati + (long)(r + sr) * K + kt + ske),
          (__attribute__((address_space(3))) unsigned int*)(&sA[r * 32]),
          16, 0, 0);
      __builtin_amdgcn_global_load_lds(
          (const __attribute__((address_space(1))) unsigned int*)(
              Bti + (long)(r + sr) * K + kt + ske),
          (__attribute__((address_space(3))) unsigned int*)(&sB[r * 32]),
          16, 0, 0);
    }
    __syncthreads();

    bf16x8 af[4], bfr[4];
#pragma unroll
    for (int mi = 0; mi < 4; ++mi)
      af[mi] = *(const bf16x8*)&sA[(wr * 64 + mi * 16 + (lane & 15)) * 32 +
                                   8 * (lane >> 4)];
#pragma unroll
    for (int ni = 0; ni < 4; ++ni)
      bfr[ni] = *(const bf16x8*)&sB[(wc * 64 + ni * 16 + (lane & 15)) * 32 +
                                    8 * (lane >> 4)];
#pragma unroll
    for (int mi = 0; mi < 4; ++mi)
#pragma unroll
      for (int ni = 0; ni < 4; ++ni)
        acc[mi][ni] = __builtin_amdgcn_mfma_f32_16x16x32_bf16(
            af[mi], bfr[ni], acc[mi][ni], 0, 0, 0);
  }

  const int rq = lane >> 4;
  const int cl = lane & 15;
#pragma unroll
  for (int ni = 0; ni < 4; ++ni) {
    const long c = nBase + wc * 64 + ni * 16 + cl;
    const float bv = bias ? bias[c] : 0.0f;
#pragma unroll
    for (int mi = 0; mi < 4; ++mi) {
      const long r = mBase + wr * 64 + mi * 16 + rq * 4;
#pragma unroll
      for (int j = 0; j < 4; ++j)
        C[(r + j) * (long)ldC + c] = acc[mi][ni][j] + bv;
    }
  }
}

// ---------- 256x256 phase-interleaved NT GEMM, frag-pipelined ----------
// BM=BN=256, BK=64, 8 waves (2x4), wave tile 128x64, mfma_f32_16x16x32_bf16.
// LDS planes [256][32] bf16, XOR-swizzled (round-4: conflicts measured 0).
// NEW (round 5): register-fragment pre-read one phase ahead. Each region:
//   [pre-read frags for NEXT phase | stage | (vmcnt) | bar | MFMA this phase | bar]
// so MFMA(p) depends only on reads issued one region earlier (counted lgkm),
// and the LDS unit serves region p+1's reads during MFMA(p)'s drain.
// vmcnt retirement ledger (per-wave, 2 loads per stage call), steady state:
//   survivors entering tile t = {B_k0(t+1), A_k1(t+1)} (4 loads)
//   P1 stages B_k1(t+1); P2: A_k0(t+2); P3: B_k0(t+2); P4: A_k1(t+2)
//   vmcnt(6)@P3 retires B_k0(t+1),A_k1(t+1)  -> P3/P4 pre-reads of tile t+1 OK
//   vmcnt(4)@P4 retires B_k1(t+1)            -> P2(t+1) b-read OK
//   tail: vmcnt(0)@P4 when t+2>=NT (retires B_k1(NT-1) which vmcnt(4) would miss)
__global__ __launch_bounds__(512, 2) void gemm256_bt(
    const unsigned short* __restrict__ A,  // [M][K] bf16, K-contiguous
    const unsigned short* __restrict__ B,  // [N][K] bf16, K-contiguous
    float* __restrict__ C,                 // [M][ldC] fp32
    const float* __restrict__ bias,        // [>=N] fp32 or nullptr
    int K, int ldC) {
  __shared__ __align__(16) unsigned short lds[2][2][2][256 * 32];  // 128 KiB

  const int tid = threadIdx.x;
  const int lane = tid & 63;
  const int w = tid >> 6;  // wave 0..7
  const int wr = w >> 2;   // 0..1
  const int wc = w & 3;    // 0..3
  const long mBase = (long)blockIdx.x * 256;
  const long nBase = (long)blockIdx.y * 256;
  const int NT = K >> 6;  // K-tiles of 64

  const int rl = lane & 15;
  const int koffR = ((lane >> 4) * 8) ^ (((rl >> 1) & 3) << 3);
  const int skel = ((lane & 3) * 8) ^ (((lane >> 3) & 3) << 3);

  auto stage = [&](const unsigned short* __restrict__ G, long rBase, int kcol0,
                   unsigned short* dplane) {
#pragma unroll
    for (int j = 0; j < 2; ++j) {
      const unsigned short* src = G +
          (rBase + j * 128 + w * 16 + (lane >> 2)) * (long)K + kcol0 + skel;
      __builtin_amdgcn_global_load_lds(
          (const __attribute__((address_space(1))) unsigned int*)src,
          (__attribute__((address_space(3))) unsigned int*)(
              dplane + (j * 128 + w * 16) * 32),
          16, 0, 0);
    }
  };
#define LDF(plane, rowexpr) (*(const bf16x8*)&(plane)[(rowexpr)*32 + koffR])

  f32x4 acc[8][4] = {};
  bf16x8 afA[8], afB[8], p0, p1, q0, q1;

  // ---- prologue: tile0 fully + tile1 {A_k0,B_k0,A_k1}; retire tile0 ----
  stage(A, mBase, 0, &lds[0][0][0][0]);
  stage(B, nBase, 0, &lds[0][1][0][0]);
  stage(A, mBase, 32, &lds[0][0][1][0]);
  stage(B, nBase, 32, &lds[0][1][1][0]);
  if (NT > 1) {
    stage(A, mBase, 64, &lds[1][0][0][0]);
    stage(B, nBase, 64, &lds[1][1][0][0]);
    stage(A, mBase, 96, &lds[1][0][1][0]);
  }
  asm volatile("s_waitcnt vmcnt(6)" ::: "memory");
  __builtin_amdgcn_s_barrier();
  // pre-read af_k0(0) + b for P1(0)
#pragma unroll
  for (int mi = 0; mi < 8; ++mi)
    afA[mi] = LDF(&lds[0][0][0][0], wr * 128 + mi * 16 + rl);
  p0 = LDF(&lds[0][1][0][0], wc * 64 + rl);
  p1 = LDF(&lds[0][1][0][0], wc * 64 + 16 + rl);

  for (int t = 0; t < NT; ++t) {
    const int cur = t & 1;
    unsigned short* A0 = &lds[cur][0][0][0];
    unsigned short* A1 = &lds[cur][0][1][0];
    unsigned short* B0 = &lds[cur][1][0][0];
    unsigned short* B1 = &lds[cur][1][1][0];
    unsigned short* nA0 = &lds[cur ^ 1][0][0][0];
    unsigned short* nB0 = &lds[cur ^ 1][1][0][0];
    unsigned short* nB1 = &lds[cur ^ 1][1][1][0];

    // ---- region P1: pre-read b_P2 + af_k1[0..3]; MFMA ksub0/n-half0 ----
    q0 = LDF(B0, wc * 64 + 32 + rl);
    q1 = LDF(B0, wc * 64 + 48 + rl);
#pragma unroll
    for (int mi = 0; mi < 4; ++mi)
      afB[mi] = LDF(A1, wr * 128 + mi * 16 + rl);
    if (t + 1 < NT) stage(B, nBase, ((t + 1) << 6) + 32, nB1);
    __builtin_amdgcn_s_barrier();
    __builtin_amdgcn_s_setprio(1);
#pragma unroll
    for (int mi = 0; mi < 8; ++mi)
      acc[mi][0] = __builtin_amdgcn_mfma_f32_16x16x32_bf16(afA[mi], p0,
                                                           acc[mi][0], 0, 0, 0);
#pragma unroll
    for (int mi = 0; mi < 8; ++mi)
      acc[mi][1] = __builtin_amdgcn_mfma_f32_16x16x32_bf16(afA[mi], p1,
                                                           acc[mi][1], 0, 0, 0);
    __builtin_amdgcn_s_setprio(0);
    __builtin_amdgcn_s_barrier();

    // ---- region P2: pre-read af_k1[4..7] + b_P3; MFMA ksub0/n-half1 ----
#pragma unroll
    for (int mi = 4; mi < 8; ++mi)
      afB[mi] = LDF(A1, wr * 128 + mi * 16 + rl);
    p0 = LDF(B1, wc * 64 + rl);
    p1 = LDF(B1, wc * 64 + 16 + rl);
    if (t + 2 < NT) stage(A, mBase, (t + 2) << 6, A0);
    __builtin_amdgcn_s_barrier();
    __builtin_amdgcn_s_setprio(1);
#pragma unroll
    for (int mi = 0; mi < 8; ++mi)
      acc[mi][2] = __builtin_amdgcn_mfma_f32_16x16x32_bf16(afA[mi], q0,
                                                           acc[mi][2], 0, 0, 0);
#pragma unroll
    for (int mi = 0; mi < 8; ++mi)
      acc[mi][3] = __builtin_amdgcn_mfma_f32_16x16x32_bf16(afA[mi], q1,
                                                           acc[mi][3], 0, 0, 0);
    __builtin_amdgcn_s_setprio(0);
    __builtin_amdgcn_s_barrier();

    // ---- region P3: pre-read b_P4 + af_k0(t+1)[0..3]; MFMA ksub1/n-half0 ----
    q0 = LDF(B1, wc * 64 + 32 + rl);
    q1 = LDF(B1, wc * 64 + 48 + rl);
    if (t + 2 < NT) stage(B, nBase, (t + 2) << 6, B0);
    asm volatile("s_waitcnt vmcnt(6)" ::: "memory");
    if (t + 1 < NT) {
#pragma unroll
      for (int mi = 0; mi < 4; ++mi)
        afA[mi] = LDF(nA0, wr * 128 + mi * 16 + rl);
    }
    __builtin_amdgcn_s_barrier();
    __builtin_amdgcn_s_setprio(1);
#pragma unroll
    for (int mi = 0; mi < 8; ++mi)
      acc[mi][0] = __builtin_amdgcn_mfma_f32_16x16x32_bf16(afB[mi], p0,
                                                           acc[mi][0], 0, 0, 0);
#pragma unroll
    for (int mi = 0; mi < 8; ++mi)
      acc[mi][1] = __builtin_amdgcn_mfma_f32_16x16x32_bf16(afB[mi], p1,
                                                           acc[mi][1], 0, 0, 0);
    __builtin_amdgcn_s_setprio(0);
    __builtin_amdgcn_s_barrier();

    // ---- region P4: pre-read af_k0(t+1)[4..7] + b_P1(t+1); MFMA ksub1/n-half1 ----
    if (t + 2 < NT) stage(A, mBase, ((t + 2) << 6) + 32, A1);
    if (t + 2 < NT)
      asm volatile("s_waitcnt vmcnt(4)" ::: "memory");
    else
      asm volatile("s_waitcnt vmcnt(0)" ::: "memory");
    if (t + 1 < NT) {
#pragma unroll
      for (int mi = 4; mi < 8; ++mi)
        afA[mi] = LDF(nA0, wr * 128 + mi * 16 + rl);
      p0 = LDF(nB0, wc * 64 + rl);
      p1 = LDF(nB0, wc * 64 + 16 + rl);
    }
    __builtin_amdgcn_s_barrier();
    __builtin_amdgcn_s_setprio(1);
#pragma unroll
    for (int mi = 0; mi < 8; ++mi)
      acc[mi][2] = __builtin_amdgcn_mfma_f32_16x16x32_bf16(afB[mi], q0,
                                                           acc[mi][2], 0, 0, 0);
#pragma unroll
    for (int mi = 0; mi < 8; ++mi)
      acc[mi][3] = __builtin_amdgcn_mfma_f32_16x16x32_bf16(afB[mi], q1,
                                                           acc[mi][3], 0, 0, 0);
    __builtin_amdgcn_s_setprio(0);
    __builtin_amdgcn_s_barrier();
  }
#undef LDF

  // ---- epilogue: C/D frag mapping col=lane&15, row=4*(lane>>4)+reg [m89] ----
  const int rq = lane >> 4;
  const int cl = lane & 15;
#pragma unroll
  for (int ni = 0; ni < 4; ++ni) {
    const long c = nBase + wc * 64 + ni * 16 + cl;
    const float bv = bias ? bias[c] : 0.0f;
#pragma unroll
    for (int mi = 0; mi < 8; ++mi) {
      const long r = mBase + wr * 128 + mi * 16 + rq * 4;
#pragma unroll
      for (int j = 0; j < 4; ++j)
        C[(r + j) * (long)ldC + c] = acc[mi][ni][j] + bv;
    }
  }
}

// ---------- causal cumulative mean (chunked scan) ----------
__global__ void chunk_sums(const float* __restrict__ V,
                           float* __restrict__ part) {
  const int bc = blockIdx.x;
  const int b = bc >> 7;
  const int c = bc & (NC - 1);
  const int d0 = threadIdx.x * 4;
  const float* vp = V + ((size_t)b * SEQ + (size_t)c * CL) * DIMS + d0;
  float4 s = {0.f, 0.f, 0.f, 0.f};
#pragma unroll
  for (int l = 0; l < CL; ++l) {
    float4 v = *(const float4*)(vp + (size_t)l * DIMS);
    s.x += v.x; s.y += v.y; s.z += v.z; s.w += v.w;
  }
  float* pp = part + ((size_t)b * DIMS + d0) * NC + c;
  pp[0 * NC] = s.x; pp[1 * NC] = s.y; pp[2 * NC] = s.z; pp[3 * NC] = s.w;
}

__global__ void chunk_scan(float* __restrict__ part) {
  const int g = blockIdx.x * blockDim.x + threadIdx.x;
  float* p = part + (size_t)g * NC;
  float run = 0.f;
#pragma unroll 4
  for (int c = 0; c < NC; ++c) {
    float t = p[c];
    p[c] = run;
    run += t;
  }
}

__global__ void cum_avg(const float* __restrict__ V,
                        const float* __restrict__ part,
                        unsigned short* __restrict__ avgB) {
  const int bc = blockIdx.x;
  const int b = bc >> 7;
  const int c = bc & (NC - 1);
  const int d0 = threadIdx.x * 4;
  const float* pp = part + ((size_t)b * DIMS + d0) * NC + c;
  float4 run = {pp[0 * NC], pp[1 * NC], pp[2 * NC], pp[3 * NC]};
  const float* vp = V + ((size_t)b * SEQ + (size_t)c * CL) * DIMS + d0;
  unsigned short* op = avgB + ((size_t)b * SEQ + (size_t)c * CL) * DIMS + d0;
#pragma unroll
  for (int l = 0; l < CL; ++l) {
    float4 v = *(const float4*)(vp + (size_t)l * DIMS);
    run.x += v.x; run.y += v.y; run.z += v.z; run.w += v.w;
    const float inv = 1.0f / (float)(c * CL + l + 1);
    ushort4 o = {f2bf(run.x * inv), f2bf(run.y * inv), f2bf(run.z * inv),
                 f2bf(run.w * inv)};
    *(ushort4*)(op + (size_t)l * DIMS) = o;
  }
}

// ---------- workspace layout (bytes, 256-aligned) ----------
#define WS_EB 0UL                   // bf16 [4096][1024]   8,388,608
#define WS_WV 8388608UL             // bf16 [1024][1024]   2,097,152
#define WS_WO 10485760UL            // bf16 [32000][1024] 65,536,000
#define WS_V 76021760UL             // f32  [4096][1024]  16,777,216
#define WS_AVG 92798976UL           // bf16 [4096][1024]   8,388,608
#define WS_PART 101187584UL         // f32  [2][1024][128] 1,048,576
#define WS_NEED 102236160UL

extern "C" void kernel_launch(void* const* d_in, const int* in_sizes, int n_in,
                              void* d_out, int out_size, void* d_ws,
                              size_t ws_size, hipStream_t stream) {
  const int* idx = (const int*)d_in[0];
  const float* emb = (const float*)d_in[1];
  const float* W_V = (const float*)d_in[2];
  const float* W_out = (const float*)d_in[3];
  const float* b_out = (const float*)d_in[4];
  float* out = (float*)d_out;

  if (ws_size < WS_NEED) return;

  char* ws = (char*)d_ws;
  unsigned short* eB = (unsigned short*)(ws + WS_EB);
  unsigned short* wvB = (unsigned short*)(ws + WS_WV);
  unsigned short* woB = (unsigned short*)(ws + WS_WO);
  float* V = (float*)(ws + WS_V);
  unsigned short* avgB = (unsigned short*)(ws + WS_AVG);
  float* part = (float*)(ws + WS_PART);

  hipLaunchKernelGGL(cvt_f32_bf16, dim3(1024), dim3(256), 0, stream, W_V, wvB,
                     (DIMS * DIMS) / 4);
  hipLaunchKernelGGL(cvt_f32_bf16, dim3(2048), dim3(256), 0, stream, W_out,
                     woB, (VOCAB * DIMS) / 4);
  hipLaunchKernelGGL(gather_emb, dim3(ROWS), dim3(256), 0, stream, idx, emb,
                     eB);
  // V = e @ W_V^T  (M=4096, N=1024, K=1024) — old 128^2 kernel, 256 blocks
  hipLaunchKernelGGL(gemm_bt, dim3(ROWS / 128, DIMS / 128), dim3(256), 0,
                     stream, eB, wvB, V, (const float*)nullptr, DIMS, DIMS);
  hipLaunchKernelGGL(chunk_sums, dim3(BATCH * NC), dim3(256), 0, stream, V,
                     part);
  hipLaunchKernelGGL(chunk_scan, dim3((BATCH * DIMS) / 256), dim3(256), 0,
                     stream, part);
  hipLaunchKernelGGL(cum_avg, dim3(BATCH * NC), dim3(256), 0, stream, V, part,
                     avgB);
  // out = avg @ W_out^T + b_out  (M=4096, N=32000, K=1024)
  // grid x = m-tiles (16, fastest): concurrent B working set ~8 MB,
  // W_out streams once (round-2 counter evidence).
  hipLaunchKernelGGL(gemm256_bt, dim3(ROWS / 256, VOCAB / 256), dim3(512), 0,
                     stream, avgB, woB, out, b_out, DIMS, VOCAB);
}

// Round 6
// 475.677 us; speedup vs baseline: 1.0288x; 1.0288x over previous
//
#include <hip/hip_runtime.h>
#include <hip/hip_bf16.h>

typedef __attribute__((ext_vector_type(4))) float f32x4;
typedef __attribute__((ext_vector_type(8))) short bf16x8;

#define VOCAB 32000
#define DIMS 1024
#define BATCH 2
#define SEQ 2048
#define ROWS (BATCH * SEQ)  // 4096
#define NC 128              // cumsum chunks per sequence
#define CL 16               // chunk length; NC*CL == SEQ

// ---------- helpers ----------
static __device__ __forceinline__ unsigned short f2bf(float f) {
  unsigned int u = __float_as_uint(f);
  unsigned int r = u + 0x7fffu + ((u >> 16) & 1u);
  return (unsigned short)(r >> 16);
}

// ---------- fp32 -> bf16 bulk convert ----------
__global__ void cvt_f32_bf16(const float* __restrict__ src,
                             unsigned short* __restrict__ dst, int n4) {
  int i = blockIdx.x * blockDim.x + threadIdx.x;
  int stride = gridDim.x * blockDim.x;
  for (; i < n4; i += stride) {
    float4 v = ((const float4*)src)[i];
    ushort4 o = {f2bf(v.x), f2bf(v.y), f2bf(v.z), f2bf(v.w)};
    ((ushort4*)dst)[i] = o;
  }
}

// ---------- embedding gather + convert ----------
__global__ void gather_emb(const int* __restrict__ idx,
                           const float* __restrict__ emb,
                           unsigned short* __restrict__ eB) {
  const int row = blockIdx.x;
  const int t = threadIdx.x;
  const int token = idx[row];
  const float4* src = (const float4*)(emb + (size_t)token * DIMS);
  float4 v = src[t];
  ushort4 o = {f2bf(v.x), f2bf(v.y), f2bf(v.z), f2bf(v.w)};
  ((ushort4*)(eB + (size_t)row * DIMS))[t] = o;
}

// ---------- old 128x128 NT GEMM (kept for the small V projection) ----------
__global__ __launch_bounds__(256) void gemm_bt(
    const unsigned short* __restrict__ A, const unsigned short* __restrict__ B,
    float* __restrict__ C, const float* __restrict__ bias, int K, int ldC) {
  __shared__ __align__(16) unsigned short sA[128 * 32];
  __shared__ __align__(16) unsigned short sB[128 * 32];

  const int tid = threadIdx.x;
  const int lane = tid & 63;
  const int w = tid >> 6;
  const int wr = w >> 1;
  const int wc = w & 1;
  const long mBase = (long)blockIdx.x * 128;
  const long nBase = (long)blockIdx.y * 128;

  const unsigned short* Ati = A + mBase * K;
  const unsigned short* Bti = B + nBase * K;

  const int srow0 = w * 32;
  const int sr = lane >> 2;
  const int ske = (lane & 3) * 8;

  f32x4 acc[4][4] = {};

  for (int kt = 0; kt < K; kt += 32) {
    __syncthreads();
#pragma unroll
    for (int i = 0; i < 2; ++i) {
      const int r = srow0 + i * 16;
      __builtin_amdgcn_global_load_lds(
          (const __attribute__((address_space(1))) unsigned int*)(
              Ati + (long)(r + sr) * K + kt + ske),
          (__attribute__((address_space(3))) unsigned int*)(&sA[r * 32]),
          16, 0, 0);
      __builtin_amdgcn_global_load_lds(
          (const __attribute__((address_space(1))) unsigned int*)(
              Bti + (long)(r + sr) * K + kt + ske),
          (__attribute__((address_space(3))) unsigned int*)(&sB[r * 32]),
          16, 0, 0);
    }
    __syncthreads();

    bf16x8 af[4], bfr[4];
#pragma unroll
    for (int mi = 0; mi < 4; ++mi)
      af[mi] = *(const bf16x8*)&sA[(wr * 64 + mi * 16 + (lane & 15)) * 32 +
                                   8 * (lane >> 4)];
#pragma unroll
    for (int ni = 0; ni < 4; ++ni)
      bfr[ni] = *(const bf16x8*)&sB[(wc * 64 + ni * 16 + (lane & 15)) * 32 +
                                    8 * (lane >> 4)];
#pragma unroll
    for (int mi = 0; mi < 4; ++mi)
#pragma unroll
      for (int ni = 0; ni < 4; ++ni)
        acc[mi][ni] = __builtin_amdgcn_mfma_f32_16x16x32_bf16(
            af[mi], bfr[ni], acc[mi][ni], 0, 0, 0);
  }

  const int rq = lane >> 4;
  const int cl = lane & 15;
#pragma unroll
  for (int ni = 0; ni < 4; ++ni) {
    const long c = nBase + wc * 64 + ni * 16 + cl;
    const float bv = bias ? bias[c] : 0.0f;
#pragma unroll
    for (int mi = 0; mi < 4; ++mi) {
      const long r = mBase + wr * 64 + mi * 16 + rq * 4;
#pragma unroll
      for (int j = 0; j < 4; ++j)
        C[(r + j) * (long)ldC + c] = acc[mi][ni][j] + bv;
    }
  }
}

// ---------- 256x256 single-barrier-window NT GEMM (big output projection) ----
// BM=BN=256, BK=32, 8 waves (2x4), wave tile 128x64, mfma_f32_16x16x32_bf16.
// ROUND 6 restructure: rounds 3-5 showed the [reads | bar | MFMA | bar] phase
// pair forces pipe ALTERNATION (LDS idle during MFMA, matrix pipe idle during
// reads; per-phase 1786 cyc ~ 576 LDS + 620 MFMA + barrier overhead, serial).
// Fix: ONE barrier per BK=32 window; stage + 12 ds_reads + 32 MFMAs coexist in
// the window, waves drift -> LDS unit and matrix pipe overlap (m114 TLP).
//  - triple-buffered LDS (96 KiB): window t reads buf[t%3], stages t+2 into
//    buf[(t+2)%3]. WAR safe: buf[(t+2)%3]'s last readers were window t-1,
//    done before bar(t).
//  - RAW via counted vmcnt BEFORE bar: vmcnt(4) leaves only tile-(t+1)'s 4
//    stage-loads in flight, so tile-t's writes are retired; barrier makes
//    them visible to all waves. Tail t==NT-1 uses vmcnt(0).
//  - XOR-swizzled planes [256][32] (round-4: bank conflicts measured 0).
//  - compiler emits counted lgkmcnt for ds_read->MFMA (m97 evidence).
__global__ __launch_bounds__(512, 2) void gemm256_bt(
    const unsigned short* __restrict__ A,  // [M][K] bf16, K-contiguous
    const unsigned short* __restrict__ B,  // [N][K] bf16, K-contiguous
    float* __restrict__ C,                 // [M][ldC] fp32
    const float* __restrict__ bias,        // [>=N] fp32 or nullptr
    int K, int ldC) {
  __shared__ __align__(16) unsigned short lds[3][2][256 * 32];  // 96 KiB

  const int tid = threadIdx.x;
  const int lane = tid & 63;
  const int w = tid >> 6;  // wave 0..7
  const int wr = w >> 2;   // 0..1
  const int wc = w & 3;    // 0..3
  const long mBase = (long)blockIdx.x * 256;
  const long nBase = (long)blockIdx.y * 256;
  const int NT = K >> 5;  // BK=32 windows

  const int rl = lane & 15;
  const int koffR = ((lane >> 4) * 8) ^ (((rl >> 1) & 3) << 3);
  const int skel = ((lane & 3) * 8) ^ (((lane >> 3) & 3) << 3);

  // stage one 16KB plane (256 rows x 32 cols bf16): 2 x global_load_lds.
  // LDS dest linear (gload_lds requirement); global source col pre-swizzled.
  auto stage = [&](const unsigned short* __restrict__ G, long rBase, int kcol0,
                   unsigned short* dplane) {
#pragma unroll
    for (int j = 0; j < 2; ++j) {
      const unsigned short* src = G +
          (rBase + j * 128 + w * 16 + (lane >> 2)) * (long)K + kcol0 + skel;
      __builtin_amdgcn_global_load_lds(
          (const __attribute__((address_space(1))) unsigned int*)src,
          (__attribute__((address_space(3))) unsigned int*)(
              dplane + (j * 128 + w * 16) * 32),
          16, 0, 0);
    }
  };
#define LDF(plane, rowexpr) (*(const bf16x8*)&(plane)[(rowexpr)*32 + koffR])

  f32x4 acc[8][4] = {};

  // ---- prologue: stage tiles 0 and 1 (8 loads/wave outstanding) ----
  stage(A, mBase, 0, &lds[0][0][0]);
  stage(B, nBase, 0, &lds[0][1][0]);
  stage(A, mBase, 32, &lds[1][0][0]);
  stage(B, nBase, 32, &lds[1][1][0]);

  for (int t = 0; t < NT; ++t) {
    unsigned short* Ap = &lds[t % 3][0][0];
    unsigned short* Bp = &lds[t % 3][1][0];

    // retire our tile-t stage writes, then join all waves (visibility)
    if (t == NT - 1)
      asm volatile("s_waitcnt vmcnt(0)" ::: "memory");
    else
      asm volatile("s_waitcnt vmcnt(4)" ::: "memory");
    __builtin_amdgcn_s_barrier();

    // prefetch tile t+2 into buf[(t+2)%3] (2-window-deep pipeline)
    if (t + 2 < NT) {
      stage(A, mBase, (t + 2) << 5, &lds[(t + 2) % 3][0][0]);
      stage(B, nBase, (t + 2) << 5, &lds[(t + 2) % 3][1][0]);
    }

    // 12 frag reads for this window
    bf16x8 afA[8], b0, b1, b2, b3;
#pragma unroll
    for (int mi = 0; mi < 8; ++mi)
      afA[mi] = LDF(Ap, wr * 128 + mi * 16 + rl);
    b0 = LDF(Bp, wc * 64 + rl);
    b1 = LDF(Bp, wc * 64 + 16 + rl);
    b2 = LDF(Bp, wc * 64 + 32 + rl);
    b3 = LDF(Bp, wc * 64 + 48 + rl);

    // 32 MFMAs (compiler inserts counted lgkmcnt per cluster)
    __builtin_amdgcn_s_setprio(1);
#pragma unroll
    for (int mi = 0; mi < 8; ++mi)
      acc[mi][0] = __builtin_amdgcn_mfma_f32_16x16x32_bf16(afA[mi], b0,
                                                           acc[mi][0], 0, 0, 0);
#pragma unroll
    for (int mi = 0; mi < 8; ++mi)
      acc[mi][1] = __builtin_amdgcn_mfma_f32_16x16x32_bf16(afA[mi], b1,
                                                           acc[mi][1], 0, 0, 0);
#pragma unroll
    for (int mi = 0; mi < 8; ++mi)
      acc[mi][2] = __builtin_amdgcn_mfma_f32_16x16x32_bf16(afA[mi], b2,
                                                           acc[mi][2], 0, 0, 0);
#pragma unroll
    for (int mi = 0; mi < 8; ++mi)
      acc[mi][3] = __builtin_amdgcn_mfma_f32_16x16x32_bf16(afA[mi], b3,
                                                           acc[mi][3], 0, 0, 0);
    __builtin_amdgcn_s_setprio(0);
  }
#undef LDF

  // ---- epilogue: C/D frag mapping col=lane&15, row=4*(lane>>4)+reg [m89] ----
  const int rq = lane >> 4;
  const int cl = lane & 15;
#pragma unroll
  for (int ni = 0; ni < 4; ++ni) {
    const long c = nBase + wc * 64 + ni * 16 + cl;
    const float bv = bias ? bias[c] : 0.0f;
#pragma unroll
    for (int mi = 0; mi < 8; ++mi) {
      const long r = mBase + wr * 128 + mi * 16 + rq * 4;
#pragma unroll
      for (int j = 0; j < 4; ++j)
        C[(r + j) * (long)ldC + c] = acc[mi][ni][j] + bv;
    }
  }
}

// ---------- causal cumulative mean (chunked scan) ----------
__global__ void chunk_sums(const float* __restrict__ V,
                           float* __restrict__ part) {
  const int bc = blockIdx.x;
  const int b = bc >> 7;
  const int c = bc & (NC - 1);
  const int d0 = threadIdx.x * 4;
  const float* vp = V + ((size_t)b * SEQ + (size_t)c * CL) * DIMS + d0;
  float4 s = {0.f, 0.f, 0.f, 0.f};
#pragma unroll
  for (int l = 0; l < CL; ++l) {
    float4 v = *(const float4*)(vp + (size_t)l * DIMS);
    s.x += v.x; s.y += v.y; s.z += v.z; s.w += v.w;
  }
  float* pp = part + ((size_t)b * DIMS + d0) * NC + c;
  pp[0 * NC] = s.x; pp[1 * NC] = s.y; pp[2 * NC] = s.z; pp[3 * NC] = s.w;
}

__global__ void chunk_scan(float* __restrict__ part) {
  const int g = blockIdx.x * blockDim.x + threadIdx.x;
  float* p = part + (size_t)g * NC;
  float run = 0.f;
#pragma unroll 4
  for (int c = 0; c < NC; ++c) {
    float t = p[c];
    p[c] = run;
    run += t;
  }
}

__global__ void cum_avg(const float* __restrict__ V,
                        const float* __restrict__ part,
                        unsigned short* __restrict__ avgB) {
  const int bc = blockIdx.x;
  const int b = bc >> 7;
  const int c = bc & (NC - 1);
  const int d0 = threadIdx.x * 4;
  const float* pp = part + ((size_t)b * DIMS + d0) * NC + c;
  float4 run = {pp[0 * NC], pp[1 * NC], pp[2 * NC], pp[3 * NC]};
  const float* vp = V + ((size_t)b * SEQ + (size_t)c * CL) * DIMS + d0;
  unsigned short* op = avgB + ((size_t)b * SEQ + (size_t)c * CL) * DIMS + d0;
#pragma unroll
  for (int l = 0; l < CL; ++l) {
    float4 v = *(const float4*)(vp + (size_t)l * DIMS);
    run.x += v.x; run.y += v.y; run.z += v.z; run.w += v.w;
    const float inv = 1.0f / (float)(c * CL + l + 1);
    ushort4 o = {f2bf(run.x * inv), f2bf(run.y * inv), f2bf(run.z * inv),
                 f2bf(run.w * inv)};
    *(ushort4*)(op + (size_t)l * DIMS) = o;
  }
}

// ---------- workspace layout (bytes, 256-aligned) ----------
#define WS_EB 0UL                   // bf16 [4096][1024]   8,388,608
#define WS_WV 8388608UL             // bf16 [1024][1024]   2,097,152
#define WS_WO 10485760UL            // bf16 [32000][1024] 65,536,000
#define WS_V 76021760UL             // f32  [4096][1024]  16,777,216
#define WS_AVG 92798976UL           // bf16 [4096][1024]   8,388,608
#define WS_PART 101187584UL         // f32  [2][1024][128] 1,048,576
#define WS_NEED 102236160UL

extern "C" void kernel_launch(void* const* d_in, const int* in_sizes, int n_in,
                              void* d_out, int out_size, void* d_ws,
                              size_t ws_size, hipStream_t stream) {
  const int* idx = (const int*)d_in[0];
  const float* emb = (const float*)d_in[1];
  const float* W_V = (const float*)d_in[2];
  const float* W_out = (const float*)d_in[3];
  const float* b_out = (const float*)d_in[4];
  float* out = (float*)d_out;

  if (ws_size < WS_NEED) return;

  char* ws = (char*)d_ws;
  unsigned short* eB = (unsigned short*)(ws + WS_EB);
  unsigned short* wvB = (unsigned short*)(ws + WS_WV);
  unsigned short* woB = (unsigned short*)(ws + WS_WO);
  float* V = (float*)(ws + WS_V);
  unsigned short* avgB = (unsigned short*)(ws + WS_AVG);
  float* part = (float*)(ws + WS_PART);

  hipLaunchKernelGGL(cvt_f32_bf16, dim3(1024), dim3(256), 0, stream, W_V, wvB,
                     (DIMS * DIMS) / 4);
  hipLaunchKernelGGL(cvt_f32_bf16, dim3(2048), dim3(256), 0, stream, W_out,
                     woB, (VOCAB * DIMS) / 4);
  hipLaunchKernelGGL(gather_emb, dim3(ROWS), dim3(256), 0, stream, idx, emb,
                     eB);
  // V = e @ W_V^T  (M=4096, N=1024, K=1024) — old 128^2 kernel, 256 blocks
  hipLaunchKernelGGL(gemm_bt, dim3(ROWS / 128, DIMS / 128), dim3(256), 0,
                     stream, eB, wvB, V, (const float*)nullptr, DIMS, DIMS);
  hipLaunchKernelGGL(chunk_sums, dim3(BATCH * NC), dim3(256), 0, stream, V,
                     part);
  hipLaunchKernelGGL(chunk_scan, dim3((BATCH * DIMS) / 256), dim3(256), 0,
                     stream, part);
  hipLaunchKernelGGL(cum_avg, dim3(BATCH * NC), dim3(256), 0, stream, V, part,
                     avgB);
  // out = avg @ W_out^T + b_out  (M=4096, N=32000, K=1024)
  // grid x = m-tiles (16, fastest): concurrent B working set ~8 MB,
  // W_out streams once (round-2 counter evidence).
  hipLaunchKernelGGL(gemm256_bt, dim3(ROWS / 256, VOCAB / 256), dim3(512), 0,
                     stream, avgB, woB, out, b_out, DIMS, VOCAB);
}

// Round 7
// 471.315 us; speedup vs baseline: 1.0384x; 1.0093x over previous
//
#include <hip/hip_runtime.h>
#include <hip/hip_bf16.h>

typedef __attribute__((ext_vector_type(4))) float f32x4;
typedef __attribute__((ext_vector_type(8))) short bf16x8;

#define VOCAB 32000
#define DIMS 1024
#define BATCH 2
#define SEQ 2048
#define ROWS (BATCH * SEQ)  // 4096
#define NC 128              // cumsum chunks per sequence
#define CL 16               // chunk length; NC*CL == SEQ

// ---------- helpers ----------
static __device__ __forceinline__ unsigned short f2bf(float f) {
  unsigned int u = __float_as_uint(f);
  unsigned int r = u + 0x7fffu + ((u >> 16) & 1u);
  return (unsigned short)(r >> 16);
}

// ---------- fp32 -> bf16 bulk convert ----------
__global__ void cvt_f32_bf16(const float* __restrict__ src,
                             unsigned short* __restrict__ dst, int n4) {
  int i = blockIdx.x * blockDim.x + threadIdx.x;
  int stride = gridDim.x * blockDim.x;
  for (; i < n4; i += stride) {
    float4 v = ((const float4*)src)[i];
    ushort4 o = {f2bf(v.x), f2bf(v.y), f2bf(v.z), f2bf(v.w)};
    ((ushort4*)dst)[i] = o;
  }
}

// ---------- embedding gather + convert ----------
__global__ void gather_emb(const int* __restrict__ idx,
                           const float* __restrict__ emb,
                           unsigned short* __restrict__ eB) {
  const int row = blockIdx.x;
  const int t = threadIdx.x;
  const int token = idx[row];
  const float4* src = (const float4*)(emb + (size_t)token * DIMS);
  float4 v = src[t];
  ushort4 o = {f2bf(v.x), f2bf(v.y), f2bf(v.z), f2bf(v.w)};
  ((ushort4*)(eB + (size_t)row * DIMS))[t] = o;
}

// ---------- old 128x128 NT GEMM (kept for the small V projection) ----------
__global__ __launch_bounds__(256) void gemm_bt(
    const unsigned short* __restrict__ A, const unsigned short* __restrict__ B,
    float* __restrict__ C, const float* __restrict__ bias, int K, int ldC) {
  __shared__ __align__(16) unsigned short sA[128 * 32];
  __shared__ __align__(16) unsigned short sB[128 * 32];

  const int tid = threadIdx.x;
  const int lane = tid & 63;
  const int w = tid >> 6;
  const int wr = w >> 1;
  const int wc = w & 1;
  const long mBase = (long)blockIdx.x * 128;
  const long nBase = (long)blockIdx.y * 128;

  const unsigned short* Ati = A + mBase * K;
  const unsigned short* Bti = B + nBase * K;

  const int srow0 = w * 32;
  const int sr = lane >> 2;
  const int ske = (lane & 3) * 8;

  f32x4 acc[4][4] = {};

  for (int kt = 0; kt < K; kt += 32) {
    __syncthreads();
#pragma unroll
    for (int i = 0; i < 2; ++i) {
      const int r = srow0 + i * 16;
      __builtin_amdgcn_global_load_lds(
          (const __attribute__((address_space(1))) unsigned int*)(
              Ati + (long)(r + sr) * K + kt + ske),
          (__attribute__((address_space(3))) unsigned int*)(&sA[r * 32]),
          16, 0, 0);
      __builtin_amdgcn_global_load_lds(
          (const __attribute__((address_space(1))) unsigned int*)(
              Bti + (long)(r + sr) * K + kt + ske),
          (__attribute__((address_space(3))) unsigned int*)(&sB[r * 32]),
          16, 0, 0);
    }
    __syncthreads();

    bf16x8 af[4], bfr[4];
#pragma unroll
    for (int mi = 0; mi < 4; ++mi)
      af[mi] = *(const bf16x8*)&sA[(wr * 64 + mi * 16 + (lane & 15)) * 32 +
                                   8 * (lane >> 4)];
#pragma unroll
    for (int ni = 0; ni < 4; ++ni)
      bfr[ni] = *(const bf16x8*)&sB[(wc * 64 + ni * 16 + (lane & 15)) * 32 +
                                    8 * (lane >> 4)];
#pragma unroll
    for (int mi = 0; mi < 4; ++mi)
#pragma unroll
      for (int ni = 0; ni < 4; ++ni)
        acc[mi][ni] = __builtin_amdgcn_mfma_f32_16x16x32_bf16(
            af[mi], bfr[ni], acc[mi][ni], 0, 0, 0);
  }

  const int rq = lane >> 4;
  const int cl = lane & 15;
#pragma unroll
  for (int ni = 0; ni < 4; ++ni) {
    const long c = nBase + wc * 64 + ni * 16 + cl;
    const float bv = bias ? bias[c] : 0.0f;
#pragma unroll
    for (int mi = 0; mi < 4; ++mi) {
      const long r = mBase + wr * 64 + mi * 16 + rq * 4;
#pragma unroll
      for (int j = 0; j < 4; ++j)
        C[(r + j) * (long)ldC + c] = acc[mi][ni][j] + bv;
    }
  }
}

// ---------- 256x256 m201-geometry 4-phase NT GEMM (big output projection) ----
// BM=BN=256, BK=64, 8 waves (2x4), wave tile 128x64, mfma_f32_16x16x32_bf16.
// LDS = [dbuf2][A/B][half2] planes of [128 rows][64 cols] bf16 = 128 KiB.
// Wave half-affinity: wave (wr,wc) reads ONLY A-half wr and B-half (wc>>1).
// 4 phases/K-tile (reads 12/4/8/0 b128), one half-tile staged per phase,
// ONE counted vmcnt per K-tile (ph4). Stage order & retirement ledger:
//   prologue: A0(0) A1(0) B0(0) B1(0) B0(1) A0(1); vmcnt(4) retires tile 0.
//   steady:  ph1->A1(t+1), ph2->B1(t+1), ph3->B0(t+2), ph4->A0(t+2)+vmcnt(4)
//            (12 outstanding -> keep newest 4 = {B0,A0}(t+2): tile t+1 fully
//            retired exactly before its consumption). Tail t+2>=NT: vmcnt(0).
// WAR safety of each stage target verified: the overwritten half's last
// readers are >=2 barriers upstream (A-halves read ph1+ph3, B-halves ph1+ph2).
// Swizzle (both-sides involution, round-4 scheme, conflicts measured 0):
//   LDS block b at row r holds global k-block b^(r&7); read col offset
//   (ks*32+qtr*8)^((r&7)<<3); stage global col pre-swizzled by lane.
__global__ __launch_bounds__(512, 2) void gemm256_bt(
    const unsigned short* __restrict__ A,  // [M][K] bf16, K-contiguous
    const unsigned short* __restrict__ B,  // [N][K] bf16, K-contiguous
    float* __restrict__ C,                 // [M][ldC] fp32
    const float* __restrict__ bias,        // [>=N] fp32 or nullptr
    int K, int ldC) {
  __shared__ __align__(16) unsigned short lds[2][2][2][128 * 64];  // 128 KiB

  const int tid = threadIdx.x;
  const int lane = tid & 63;
  const int w = tid >> 6;  // wave 0..7
  const int wr = w >> 2;   // 0..1 -> A-half
  const int wc = w & 3;    // 0..3 -> B-half wc>>1, strip wc&1
  const long mBase = (long)blockIdx.x * 256;
  const long nBase = (long)blockIdx.y * 256;
  const int NT = K >> 6;  // BK=64 K-tiles (NT>=2)

  const int rl = lane & 15;
  const int qtr = lane >> 4;            // 0..3
  const int swz = (rl & 7) << 3;        // read-side XOR (row&7)<<3 elements
  const int skel = ((lane & 7) ^ (lane >> 3)) << 3;  // stage-side source col

  // stage one [128][64] half-plane: 2 x global_load_lds, 512 threads x 16B.
  // LDS dest linear (wave-uniform base + lane*16B); global col pre-swizzled.
  auto stage = [&](const unsigned short* __restrict__ G, long rBase, int kcol0,
                   unsigned short* half) {
#pragma unroll
    for (int j = 0; j < 2; ++j) {
      const unsigned short* src =
          G + (rBase + j * 64 + w * 8 + (lane >> 3)) * (long)K + kcol0 + skel;
      __builtin_amdgcn_global_load_lds(
          (const __attribute__((address_space(1))) unsigned int*)src,
          (__attribute__((address_space(3))) unsigned int*)(half + j * 4096 +
                                                            w * 512),
          16, 0, 0);
    }
  };
#define LDF(pl, r, ks) \
  (*(const bf16x8*)&(pl)[(r) * 64 + (((ks) * 32 + qtr * 8) ^ swz)])

  f32x4 acc[8][4] = {};
  bf16x8 a[4][2], bA[2][2], bB[2][2];

  // ---- prologue ----
  stage(A, mBase, 0, &lds[0][0][0][0]);        // A0(0)
  stage(A, mBase + 128, 0, &lds[0][0][1][0]);  // A1(0)
  stage(B, nBase, 0, &lds[0][1][0][0]);        // B0(0)
  stage(B, nBase + 128, 0, &lds[0][1][1][0]);  // B1(0)
  stage(B, nBase, 64, &lds[1][1][0][0]);       // B0(1)
  stage(A, mBase, 64, &lds[1][0][0][0]);       // A0(1)
  asm volatile("s_waitcnt vmcnt(4)" ::: "memory");
  __builtin_amdgcn_s_barrier();

  for (int t = 0; t < NT; ++t) {
    const int d = t & 1, e = d ^ 1;
    const unsigned short* APl = &lds[d][0][wr][0];
    const unsigned short* BPl = &lds[d][1][wc >> 1][0];
    const int bro = (wc & 1) * 64;
    const int kc1 = (t + 1) << 6, kc2 = (t + 2) << 6;

    // ---- ph1: read a(mi0-3)+bA (12); stage A1(t+1) ----
#pragma unroll
    for (int mi = 0; mi < 4; ++mi)
#pragma unroll
      for (int ks = 0; ks < 2; ++ks) a[mi][ks] = LDF(APl, mi * 16 + rl, ks);
#pragma unroll
    for (int ni = 0; ni < 2; ++ni)
#pragma unroll
      for (int ks = 0; ks < 2; ++ks)
        bA[ni][ks] = LDF(BPl, bro + ni * 16 + rl, ks);
    if (t + 1 < NT) stage(A, mBase + 128, kc1, &lds[e][0][1][0]);
    __builtin_amdgcn_s_barrier();
    __builtin_amdgcn_s_setprio(1);
#pragma unroll
    for (int ks = 0; ks < 2; ++ks)
#pragma unroll
      for (int mi = 0; mi < 4; ++mi) {
        acc[mi][0] = __builtin_amdgcn_mfma_f32_16x16x32_bf16(
            a[mi][ks], bA[0][ks], acc[mi][0], 0, 0, 0);
        acc[mi][1] = __builtin_amdgcn_mfma_f32_16x16x32_bf16(
            a[mi][ks], bA[1][ks], acc[mi][1], 0, 0, 0);
      }
    __builtin_amdgcn_s_setprio(0);
    __builtin_amdgcn_s_barrier();

    // ---- ph2: read bB (4); stage B1(t+1) ----
#pragma unroll
    for (int ni = 0; ni < 2; ++ni)
#pragma unroll
      for (int ks = 0; ks < 2; ++ks)
        bB[ni][ks] = LDF(BPl, bro + (ni + 2) * 16 + rl, ks);
    if (t + 1 < NT) stage(B, nBase + 128, kc1, &lds[e][1][1][0]);
    __builtin_amdgcn_s_barrier();
    __builtin_amdgcn_s_setprio(1);
#pragma unroll
    for (int ks = 0; ks < 2; ++ks)
#pragma unroll
      for (int mi = 0; mi < 4; ++mi) {
        acc[mi][2] = __builtin_amdgcn_mfma_f32_16x16x32_bf16(
            a[mi][ks], bB[0][ks], acc[mi][2], 0, 0, 0);
        acc[mi][3] = __builtin_amdgcn_mfma_f32_16x16x32_bf16(
            a[mi][ks], bB[1][ks], acc[mi][3], 0, 0, 0);
      }
    __builtin_amdgcn_s_setprio(0);
    __builtin_amdgcn_s_barrier();

    // ---- ph3: read a(mi4-7) (8); stage B0(t+2) ----
#pragma unroll
    for (int mi = 0; mi < 4; ++mi)
#pragma unroll
      for (int ks = 0; ks < 2; ++ks)
        a[mi][ks] = LDF(APl, (mi + 4) * 16 + rl, ks);
    if (t + 2 < NT) stage(B, nBase, kc2, &lds[d][1][0][0]);
    __builtin_amdgcn_s_barrier();
    __builtin_amdgcn_s_setprio(1);
#pragma unroll
    for (int ks = 0; ks < 2; ++ks)
#pragma unroll
      for (int mi = 0; mi < 4; ++mi) {
        acc[mi + 4][0] = __builtin_amdgcn_mfma_f32_16x16x32_bf16(
            a[mi][ks], bA[0][ks], acc[mi + 4][0], 0, 0, 0);
        acc[mi + 4][1] = __builtin_amdgcn_mfma_f32_16x16x32_bf16(
            a[mi][ks], bA[1][ks], acc[mi + 4][1], 0, 0, 0);
      }
    __builtin_amdgcn_s_setprio(0);
    __builtin_amdgcn_s_barrier();

    // ---- ph4: no reads; stage A0(t+2); counted vmcnt once/K-tile ----
    if (t + 2 < NT) {
      stage(A, mBase, kc2, &lds[d][0][0][0]);
      asm volatile("s_waitcnt vmcnt(4)" ::: "memory");
    } else {
      asm volatile("s_waitcnt vmcnt(0)" ::: "memory");
    }
    __builtin_amdgcn_s_barrier();
    __builtin_amdgcn_s_setprio(1);
#pragma unroll
    for (int ks = 0; ks < 2; ++ks)
#pragma unroll
      for (int mi = 0; mi < 4; ++mi) {
        acc[mi + 4][2] = __builtin_amdgcn_mfma_f32_16x16x32_bf16(
            a[mi][ks], bB[0][ks], acc[mi + 4][2], 0, 0, 0);
        acc[mi + 4][3] = __builtin_amdgcn_mfma_f32_16x16x32_bf16(
            a[mi][ks], bB[1][ks], acc[mi + 4][3], 0, 0, 0);
      }
    __builtin_amdgcn_s_setprio(0);
    __builtin_amdgcn_s_barrier();
  }
#undef LDF

  // ---- epilogue: C/D frag mapping col=lane&15, row=4*(lane>>4)+reg [m89] ----
  const int rq = lane >> 4;
  const int cl = lane & 15;
#pragma unroll
  for (int ni = 0; ni < 4; ++ni) {
    const long c = nBase + wc * 64 + ni * 16 + cl;
    const float bv = bias ? bias[c] : 0.0f;
#pragma unroll
    for (int mi = 0; mi < 8; ++mi) {
      const long r = mBase + wr * 128 + mi * 16 + rq * 4;
#pragma unroll
      for (int j = 0; j < 4; ++j)
        C[(r + j) * (long)ldC + c] = acc[mi][ni][j] + bv;
    }
  }
}

// ---------- causal cumulative mean (chunked scan) ----------
__global__ void chunk_sums(const float* __restrict__ V,
                           float* __restrict__ part) {
  const int bc = blockIdx.x;
  const int b = bc >> 7;
  const int c = bc & (NC - 1);
  const int d0 = threadIdx.x * 4;
  const float* vp = V + ((size_t)b * SEQ + (size_t)c * CL) * DIMS + d0;
  float4 s = {0.f, 0.f, 0.f, 0.f};
#pragma unroll
  for (int l = 0; l < CL; ++l) {
    float4 v = *(const float4*)(vp + (size_t)l * DIMS);
    s.x += v.x; s.y += v.y; s.z += v.z; s.w += v.w;
  }
  float* pp = part + ((size_t)b * DIMS + d0) * NC + c;
  pp[0 * NC] = s.x; pp[1 * NC] = s.y; pp[2 * NC] = s.z; pp[3 * NC] = s.w;
}

__global__ void chunk_scan(float* __restrict__ part) {
  const int g = blockIdx.x * blockDim.x + threadIdx.x;
  float* p = part + (size_t)g * NC;
  float run = 0.f;
#pragma unroll 4
  for (int c = 0; c < NC; ++c) {
    float t = p[c];
    p[c] = run;
    run += t;
  }
}

__global__ void cum_avg(const float* __restrict__ V,
                        const float* __restrict__ part,
                        unsigned short* __restrict__ avgB) {
  const int bc = blockIdx.x;
  const int b = bc >> 7;
  const int c = bc & (NC - 1);
  const int d0 = threadIdx.x * 4;
  const float* pp = part + ((size_t)b * DIMS + d0) * NC + c;
  float4 run = {pp[0 * NC], pp[1 * NC], pp[2 * NC], pp[3 * NC]};
  const float* vp = V + ((size_t)b * SEQ + (size_t)c * CL) * DIMS + d0;
  unsigned short* op = avgB + ((size_t)b * SEQ + (size_t)c * CL) * DIMS + d0;
#pragma unroll
  for (int l = 0; l < CL; ++l) {
    float4 v = *(const float4*)(vp + (size_t)l * DIMS);
    run.x += v.x; run.y += v.y; run.z += v.z; run.w += v.w;
    const float inv = 1.0f / (float)(c * CL + l + 1);
    ushort4 o = {f2bf(run.x * inv), f2bf(run.y * inv), f2bf(run.z * inv),
                 f2bf(run.w * inv)};
    *(ushort4*)(op + (size_t)l * DIMS) = o;
  }
}

// ---------- workspace layout (bytes, 256-aligned) ----------
#define WS_EB 0UL                   // bf16 [4096][1024]   8,388,608
#define WS_WV 8388608UL             // bf16 [1024][1024]   2,097,152
#define WS_WO 10485760UL            // bf16 [32000][1024] 65,536,000
#define WS_V 76021760UL             // f32  [4096][1024]  16,777,216
#define WS_AVG 92798976UL           // bf16 [4096][1024]   8,388,608
#define WS_PART 101187584UL         // f32  [2][1024][128] 1,048,576
#define WS_NEED 102236160UL

extern "C" void kernel_launch(void* const* d_in, const int* in_sizes, int n_in,
                              void* d_out, int out_size, void* d_ws,
                              size_t ws_size, hipStream_t stream) {
  const int* idx = (const int*)d_in[0];
  const float* emb = (const float*)d_in[1];
  const float* W_V = (const float*)d_in[2];
  const float* W_out = (const float*)d_in[3];
  const float* b_out = (const float*)d_in[4];
  float* out = (float*)d_out;

  if (ws_size < WS_NEED) return;

  char* ws = (char*)d_ws;
  unsigned short* eB = (unsigned short*)(ws + WS_EB);
  unsigned short* wvB = (unsigned short*)(ws + WS_WV);
  unsigned short* woB = (unsigned short*)(ws + WS_WO);
  float* V = (float*)(ws + WS_V);
  unsigned short* avgB = (unsigned short*)(ws + WS_AVG);
  float* part = (float*)(ws + WS_PART);

  hipLaunchKernelGGL(cvt_f32_bf16, dim3(1024), dim3(256), 0, stream, W_V, wvB,
                     (DIMS * DIMS) / 4);
  hipLaunchKernelGGL(cvt_f32_bf16, dim3(2048), dim3(256), 0, stream, W_out,
                     woB, (VOCAB * DIMS) / 4);
  hipLaunchKernelGGL(gather_emb, dim3(ROWS), dim3(256), 0, stream, idx, emb,
                     eB);
  // V = e @ W_V^T  (M=4096, N=1024, K=1024) — old 128^2 kernel, 256 blocks
  hipLaunchKernelGGL(gemm_bt, dim3(ROWS / 128, DIMS / 128), dim3(256), 0,
                     stream, eB, wvB, V, (const float*)nullptr, DIMS, DIMS);
  hipLaunchKernelGGL(chunk_sums, dim3(BATCH * NC), dim3(256), 0, stream, V,
                     part);
  hipLaunchKernelGGL(chunk_scan, dim3((BATCH * DIMS) / 256), dim3(256), 0,
                     stream, part);
  hipLaunchKernelGGL(cum_avg, dim3(BATCH * NC), dim3(256), 0, stream, V, part,
                     avgB);
  // out = avg @ W_out^T + b_out  (M=4096, N=32000, K=1024)
  // grid x = m-tiles (16, fastest): concurrent B working set ~8 MB,
  // W_out streams once (round-2 counter evidence).
  hipLaunchKernelGGL(gemm256_bt, dim3(ROWS / 256, VOCAB / 256), dim3(512), 0,
                     stream, avgB, woB, out, b_out, DIMS, VOCAB);
}

// Round 8
// 468.526 us; speedup vs baseline: 1.0445x; 1.0060x over previous
//
#include <hip/hip_runtime.h>
#include <hip/hip_bf16.h>

typedef __attribute__((ext_vector_type(4))) float f32x4;
typedef __attribute__((ext_vector_type(8))) short bf16x8;

#define VOCAB 32000
#define DIMS 1024
#define BATCH 2
#define SEQ 2048
#define ROWS (BATCH * SEQ)  // 4096
#define NC 128              // cumsum chunks per sequence
#define CL 16               // chunk length; NC*CL == SEQ

// ---------- helpers ----------
static __device__ __forceinline__ unsigned short f2bf(float f) {
  unsigned int u = __float_as_uint(f);
  unsigned int r = u + 0x7fffu + ((u >> 16) & 1u);
  return (unsigned short)(r >> 16);
}

// ---------- fp32 -> bf16 bulk convert ----------
__global__ void cvt_f32_bf16(const float* __restrict__ src,
                             unsigned short* __restrict__ dst, int n4) {
  int i = blockIdx.x * blockDim.x + threadIdx.x;
  int stride = gridDim.x * blockDim.x;
  for (; i < n4; i += stride) {
    float4 v = ((const float4*)src)[i];
    ushort4 o = {f2bf(v.x), f2bf(v.y), f2bf(v.z), f2bf(v.w)};
    ((ushort4*)dst)[i] = o;
  }
}

// ---------- embedding gather + convert ----------
__global__ void gather_emb(const int* __restrict__ idx,
                           const float* __restrict__ emb,
                           unsigned short* __restrict__ eB) {
  const int row = blockIdx.x;
  const int t = threadIdx.x;
  const int token = idx[row];
  const float4* src = (const float4*)(emb + (size_t)token * DIMS);
  float4 v = src[t];
  ushort4 o = {f2bf(v.x), f2bf(v.y), f2bf(v.z), f2bf(v.w)};
  ((ushort4*)(eB + (size_t)row * DIMS))[t] = o;
}

// ---------- old 128x128 NT GEMM (kept for the small V projection) ----------
__global__ __launch_bounds__(256) void gemm_bt(
    const unsigned short* __restrict__ A, const unsigned short* __restrict__ B,
    float* __restrict__ C, const float* __restrict__ bias, int K, int ldC) {
  __shared__ __align__(16) unsigned short sA[128 * 32];
  __shared__ __align__(16) unsigned short sB[128 * 32];

  const int tid = threadIdx.x;
  const int lane = tid & 63;
  const int w = tid >> 6;
  const int wr = w >> 1;
  const int wc = w & 1;
  const long mBase = (long)blockIdx.x * 128;
  const long nBase = (long)blockIdx.y * 128;

  const unsigned short* Ati = A + mBase * K;
  const unsigned short* Bti = B + nBase * K;

  const int srow0 = w * 32;
  const int sr = lane >> 2;
  const int ske = (lane & 3) * 8;

  f32x4 acc[4][4] = {};

  for (int kt = 0; kt < K; kt += 32) {
    __syncthreads();
#pragma unroll
    for (int i = 0; i < 2; ++i) {
      const int r = srow0 + i * 16;
      __builtin_amdgcn_global_load_lds(
          (const __attribute__((address_space(1))) unsigned int*)(
              Ati + (long)(r + sr) * K + kt + ske),
          (__attribute__((address_space(3))) unsigned int*)(&sA[r * 32]),
          16, 0, 0);
      __builtin_amdgcn_global_load_lds(
          (const __attribute__((address_space(1))) unsigned int*)(
              Bti + (long)(r + sr) * K + kt + ske),
          (__attribute__((address_space(3))) unsigned int*)(&sB[r * 32]),
          16, 0, 0);
    }
    __syncthreads();

    bf16x8 af[4], bfr[4];
#pragma unroll
    for (int mi = 0; mi < 4; ++mi)
      af[mi] = *(const bf16x8*)&sA[(wr * 64 + mi * 16 + (lane & 15)) * 32 +
                                   8 * (lane >> 4)];
#pragma unroll
    for (int ni = 0; ni < 4; ++ni)
      bfr[ni] = *(const bf16x8*)&sB[(wc * 64 + ni * 16 + (lane & 15)) * 32 +
                                    8 * (lane >> 4)];
#pragma unroll
    for (int mi = 0; mi < 4; ++mi)
#pragma unroll
      for (int ni = 0; ni < 4; ++ni)
        acc[mi][ni] = __builtin_amdgcn_mfma_f32_16x16x32_bf16(
            af[mi], bfr[ni], acc[mi][ni], 0, 0, 0);
  }

  const int rq = lane >> 4;
  const int cl = lane & 15;
#pragma unroll
  for (int ni = 0; ni < 4; ++ni) {
    const long c = nBase + wc * 64 + ni * 16 + cl;
    const float bv = bias ? bias[c] : 0.0f;
#pragma unroll
    for (int mi = 0; mi < 4; ++mi) {
      const long r = mBase + wr * 64 + mi * 16 + rq * 4;
#pragma unroll
      for (int j = 0; j < 4; ++j)
        C[(r + j) * (long)ldC + c] = acc[mi][ni][j] + bv;
    }
  }
}

// ---------- 256x128 2-blocks/CU NT GEMM (big output projection) ----------
// ROUND 8: rounds 4-7 showed four different K-loop schedules ALL flatline at
// MfmaUtil ~32%. Cycle model: block time 108k cyc = K-loop (>=34k MFMA floor)
// + NON-OVERLAPPED epilogue (262KB fp32 C -> ~26k cyc) + prologue, at
// occupancy = 1 block/CU. Schedule was never binding; single-block
// serialization is. Fix = 2 blocks/CU so block A's K-loop covers block B's
// epilogue/prologue/window drains (m114 TLP).
//   BM=256 BN=128 BK=32, 8 waves (4x2), wave-tile 64x64, acc 64 regs.
//   LDS dbuf 2 x (256+128)x32 bf16 = 48 KiB  -> 2 blocks/CU (<=80 KiB).
//   __launch_bounds__(512,4): cap regs at 128/wave (acc 64 + frags 32 + addr).
//   Window: vmcnt(3) [retire tile t, keep t+1's 3 in flight] -> bar ->
//           8 ds_read_b128 + 16 MFMA -> bar -> stage(t+2) into just-read buf.
//   Ledger: prologue {0,1}=6 out; steady 6 out, vmcnt(3) retires exactly
//   tile t; tail t==NT-1 -> vmcnt(0). WAR: stage target's readers are all
//   pre-bar2. Swizzle = round-4 scheme verbatim (conflicts measured 0).
__global__ __launch_bounds__(512, 4) void gemm256x128_bt(
    const unsigned short* __restrict__ A,  // [M][K] bf16, K-contiguous
    const unsigned short* __restrict__ B,  // [N][K] bf16, K-contiguous
    float* __restrict__ C,                 // [M][ldC] fp32
    const float* __restrict__ bias,        // [>=N] fp32 or nullptr
    int K, int ldC) {
  __shared__ __align__(16) unsigned short lds[2][384 * 32];  // 48 KiB

  const int tid = threadIdx.x;
  const int lane = tid & 63;
  const int w = tid >> 6;  // wave 0..7
  const int wr = w >> 1;   // 0..3 -> A row-quarter
  const int wc = w & 1;    // 0..1 -> B col-half
  const long mBase = (long)blockIdx.x * 256;
  const long nBase = (long)blockIdx.y * 128;
  const int NT = K >> 5;  // BK=32 windows

  const int rl = lane & 15;
  const int koffR = ((lane >> 4) * 8) ^ (((rl >> 1) & 3) << 3);
  const int skel = ((lane & 3) * 8) ^ (((lane >> 3) & 3) << 3);

  // stage A(256 rows, 2 calls) + B(128 rows, 1 call) = 3 gload_lds per wave.
  // LDS dest linear (gload_lds requirement); global source col pre-swizzled.
  auto stageAB = [&](int t, unsigned short* buf) {
    const int kcol0 = t << 5;
#pragma unroll
    for (int j = 0; j < 2; ++j) {
      const unsigned short* src =
          A + (mBase + j * 128 + w * 16 + (lane >> 2)) * (long)K + kcol0 + skel;
      __builtin_amdgcn_global_load_lds(
          (const __attribute__((address_space(1))) unsigned int*)src,
          (__attribute__((address_space(3))) unsigned int*)(
              buf + (j * 128 + w * 16) * 32),
          16, 0, 0);
    }
    const unsigned short* srcB =
        B + (nBase + w * 16 + (lane >> 2)) * (long)K + kcol0 + skel;
    __builtin_amdgcn_global_load_lds(
        (const __attribute__((address_space(1))) unsigned int*)srcB,
        (__attribute__((address_space(3))) unsigned int*)(buf + 8192 + w * 512),
        16, 0, 0);
  };
#define LDF(pl, r) (*(const bf16x8*)&(pl)[(r) * 32 + koffR])

  f32x4 acc[4][4] = {};

  // ---- prologue: stage tiles 0,1 (6 loads/wave outstanding) ----
  stageAB(0, lds[0]);
  stageAB(1, lds[1]);

  for (int t = 0; t < NT; ++t) {
    unsigned short* buf = lds[t & 1];
    const unsigned short* Ap = buf;         // [256][32]
    const unsigned short* Bp = buf + 8192;  // [128][32]

    if (t == NT - 1)
      asm volatile("s_waitcnt vmcnt(0)" ::: "memory");
    else
      asm volatile("s_waitcnt vmcnt(3)" ::: "memory");
    __builtin_amdgcn_s_barrier();

    bf16x8 a[4], b[4];
#pragma unroll
    for (int mi = 0; mi < 4; ++mi) a[mi] = LDF(Ap, wr * 64 + mi * 16 + rl);
#pragma unroll
    for (int ni = 0; ni < 4; ++ni) b[ni] = LDF(Bp, wc * 64 + ni * 16 + rl);

    __builtin_amdgcn_s_setprio(1);
#pragma unroll
    for (int mi = 0; mi < 4; ++mi)
#pragma unroll
      for (int ni = 0; ni < 4; ++ni)
        acc[mi][ni] = __builtin_amdgcn_mfma_f32_16x16x32_bf16(
            a[mi], b[ni], acc[mi][ni], 0, 0, 0);
    __builtin_amdgcn_s_setprio(0);
    __builtin_amdgcn_s_barrier();

    if (t + 2 < NT) stageAB(t + 2, buf);
  }
#undef LDF

  // ---- epilogue: C/D frag mapping col=lane&15, row=4*(lane>>4)+reg [m89] ----
  const int rq = lane >> 4;
  const int cl = lane & 15;
#pragma unroll
  for (int ni = 0; ni < 4; ++ni) {
    const long c = nBase + wc * 64 + ni * 16 + cl;
    const float bv = bias ? bias[c] : 0.0f;
#pragma unroll
    for (int mi = 0; mi < 4; ++mi) {
      const long r = mBase + wr * 64 + mi * 16 + rq * 4;
#pragma unroll
      for (int j = 0; j < 4; ++j)
        C[(r + j) * (long)ldC + c] = acc[mi][ni][j] + bv;
    }
  }
}

// ---------- causal cumulative mean (chunked scan) ----------
__global__ void chunk_sums(const float* __restrict__ V,
                           float* __restrict__ part) {
  const int bc = blockIdx.x;
  const int b = bc >> 7;
  const int c = bc & (NC - 1);
  const int d0 = threadIdx.x * 4;
  const float* vp = V + ((size_t)b * SEQ + (size_t)c * CL) * DIMS + d0;
  float4 s = {0.f, 0.f, 0.f, 0.f};
#pragma unroll
  for (int l = 0; l < CL; ++l) {
    float4 v = *(const float4*)(vp + (size_t)l * DIMS);
    s.x += v.x; s.y += v.y; s.z += v.z; s.w += v.w;
  }
  float* pp = part + ((size_t)b * DIMS + d0) * NC + c;
  pp[0 * NC] = s.x; pp[1 * NC] = s.y; pp[2 * NC] = s.z; pp[3 * NC] = s.w;
}

__global__ void chunk_scan(float* __restrict__ part) {
  const int g = blockIdx.x * blockDim.x + threadIdx.x;
  float* p = part + (size_t)g * NC;
  float run = 0.f;
#pragma unroll 4
  for (int c = 0; c < NC; ++c) {
    float t = p[c];
    p[c] = run;
    run += t;
  }
}

__global__ void cum_avg(const float* __restrict__ V,
                        const float* __restrict__ part,
                        unsigned short* __restrict__ avgB) {
  const int bc = blockIdx.x;
  const int b = bc >> 7;
  const int c = bc & (NC - 1);
  const int d0 = threadIdx.x * 4;
  const float* pp = part + ((size_t)b * DIMS + d0) * NC + c;
  float4 run = {pp[0 * NC], pp[1 * NC], pp[2 * NC], pp[3 * NC]};
  const float* vp = V + ((size_t)b * SEQ + (size_t)c * CL) * DIMS + d0;
  unsigned short* op = avgB + ((size_t)b * SEQ + (size_t)c * CL) * DIMS + d0;
#pragma unroll
  for (int l = 0; l < CL; ++l) {
    float4 v = *(const float4*)(vp + (size_t)l * DIMS);
    run.x += v.x; run.y += v.y; run.z += v.z; run.w += v.w;
    const float inv = 1.0f / (float)(c * CL + l + 1);
    ushort4 o = {f2bf(run.x * inv), f2bf(run.y * inv), f2bf(run.z * inv),
                 f2bf(run.w * inv)};
    *(ushort4*)(op + (size_t)l * DIMS) = o;
  }
}

// ---------- workspace layout (bytes, 256-aligned) ----------
#define WS_EB 0UL                   // bf16 [4096][1024]   8,388,608
#define WS_WV 8388608UL             // bf16 [1024][1024]   2,097,152
#define WS_WO 10485760UL            // bf16 [32000][1024] 65,536,000
#define WS_V 76021760UL             // f32  [4096][1024]  16,777,216
#define WS_AVG 92798976UL           // bf16 [4096][1024]   8,388,608
#define WS_PART 101187584UL         // f32  [2][1024][128] 1,048,576
#define WS_NEED 102236160UL

extern "C" void kernel_launch(void* const* d_in, const int* in_sizes, int n_in,
                              void* d_out, int out_size, void* d_ws,
                              size_t ws_size, hipStream_t stream) {
  const int* idx = (const int*)d_in[0];
  const float* emb = (const float*)d_in[1];
  const float* W_V = (const float*)d_in[2];
  const float* W_out = (const float*)d_in[3];
  const float* b_out = (const float*)d_in[4];
  float* out = (float*)d_out;

  if (ws_size < WS_NEED) return;

  char* ws = (char*)d_ws;
  unsigned short* eB = (unsigned short*)(ws + WS_EB);
  unsigned short* wvB = (unsigned short*)(ws + WS_WV);
  unsigned short* woB = (unsigned short*)(ws + WS_WO);
  float* V = (float*)(ws + WS_V);
  unsigned short* avgB = (unsigned short*)(ws + WS_AVG);
  float* part = (float*)(ws + WS_PART);

  hipLaunchKernelGGL(cvt_f32_bf16, dim3(1024), dim3(256), 0, stream, W_V, wvB,
                     (DIMS * DIMS) / 4);
  hipLaunchKernelGGL(cvt_f32_bf16, dim3(2048), dim3(256), 0, stream, W_out,
                     woB, (VOCAB * DIMS) / 4);
  hipLaunchKernelGGL(gather_emb, dim3(ROWS), dim3(256), 0, stream, idx, emb,
                     eB);
  // V = e @ W_V^T  (M=4096, N=1024, K=1024) — old 128^2 kernel, 256 blocks
  hipLaunchKernelGGL(gemm_bt, dim3(ROWS / 128, DIMS / 128), dim3(256), 0,
                     stream, eB, wvB, V, (const float*)nullptr, DIMS, DIMS);
  hipLaunchKernelGGL(chunk_sums, dim3(BATCH * NC), dim3(256), 0, stream, V,
                     part);
  hipLaunchKernelGGL(chunk_scan, dim3((BATCH * DIMS) / 256), dim3(256), 0,
                     stream, part);
  hipLaunchKernelGGL(cum_avg, dim3(BATCH * NC), dim3(256), 0, stream, V, part,
                     avgB);
  // out = avg @ W_out^T + b_out  (M=4096, N=32000, K=1024)
  // grid x = m-tiles (16, fastest): concurrent B working set small,
  // W_out streams once (round-2 counter evidence).
  hipLaunchKernelGGL(gemm256x128_bt, dim3(ROWS / 256, VOCAB / 128), dim3(512),
                     0, stream, avgB, woB, out, b_out, DIMS, VOCAB);
}